// Round 3
// baseline (80.224 us; speedup 1.0000x reference)
//
#include <hip/hip_runtime.h>
#include <math.h>

// Triangle-triangle intersection, bit-exact vs the numpy/JAX reference:
//  - EPS snap of near-plane distances at 1e-6, reference op order, fp
//    contract OFF, IEEE divides (snap threshold sits inside dot-product
//    cancellation noise; near-tie interval comparisons need exact rounding).
//  - M is bitwise symmetric under pair swap (role swap negates D=cross(na,nb)
//    but |D| and both triangle intervals are unchanged); reference computes
//    triu and mirrors -> we compute tiles with tr<=tc and write both copies.
//  - One pair per lane (32x32 tile, 1024-thread block): max wave parallelism,
//    shortest serial chains. R2's 4-pairs-per-thread variant was latency-bound.

static constexpr float EPS_SNAP = 1e-6f;
static constexpr int TS = 32;  // tile size; n=2048 divisible

__device__ __forceinline__ float snapz(float x) {
    return (fabsf(x) < EPS_SNAP) ? 0.0f : x;
}

// Interval of the intersection line covered by one triangle (reference order).
__device__ __forceinline__ void tri_interval(const float p[3], const float d[3],
                                             float& tmin, float& tmax) {
#pragma clang fp contract(off)
    tmin = INFINITY;
    tmax = -INFINITY;
#pragma unroll
    for (int e = 0; e < 3; ++e) {
        const int i0 = e;
        const int i1 = (e + 1) % 3;  // edges (0,1),(1,2),(2,0)
        const float di = d[i0], dj = d[i1];
        const float pi = p[i0], pj = p[i1];
        const bool valid = (di * dj <= 0.0f) && !((di == 0.0f) && (dj == 0.0f));
        const float denom = di - dj;
        const float dsafe = (denom == 0.0f) ? 1.0f : denom;
        const float t = pi + ((pj - pi) * di) / dsafe;  // ((pj-pi)*di)/denom
        if (valid) {
            tmin = fminf(tmin, t);
            tmax = fmaxf(tmax, t);
        }
    }
}

// Pre-pass: per-triangle plane normal + offset, same arithmetic order as ref.
__global__ __launch_bounds__(256) void plane_kernel(
    const float* __restrict__ tri, float4* __restrict__ planes, int n)
{
#pragma clang fp contract(off)
    const int i = blockIdx.x * 256 + threadIdx.x;
    if (i >= n) return;
    const float* A = tri + (size_t)i * 9;
    float Av[9];
#pragma unroll
    for (int k = 0; k < 9; ++k) Av[k] = A[k];
    const float e1x = Av[3] - Av[0], e1y = Av[4] - Av[1], e1z = Av[5] - Av[2];
    const float e2x = Av[6] - Av[0], e2y = Av[7] - Av[1], e2z = Av[8] - Av[2];
    const float nx = e1y * e2z - e1z * e2y;
    const float ny = e1z * e2x - e1x * e2z;
    const float nz = e1x * e2y - e1y * e2x;
    const float d = -(((nx * Av[0]) + (ny * Av[1])) + (nz * Av[2]));
    planes[i] = make_float4(nx, ny, nz, d);
}

// Main: one pair per lane. 32x32 triu tiles, blockDim (32,32).
__global__ __launch_bounds__(1024) void tile_kernel(
    const float* __restrict__ tri, const float4* __restrict__ planes,
    float* __restrict__ out, int n)
{
#pragma clang fp contract(off)
    const int tc = blockIdx.x, tr = blockIdx.y;
    if (tr > tc) return;  // mirror handled by the upper tile
    const int C = tc * TS, R = tr * TS;

    __shared__ float As[TS][13];        // row triangles: 9 verts + plane
    __shared__ float Sres[TS][TS + 1];  // result tile for the mirror transpose

    const int tx = threadIdx.x;  // column in tile
    const int ty = threadIdx.y;  // row in tile

    // Stage row triangles + planes into LDS (row 0 of threads).
    if (ty == 0) {
        const float* a = tri + (size_t)(R + tx) * 9;
#pragma unroll
        for (int k = 0; k < 9; ++k) As[tx][k] = a[k];
        const float4 p = planes[R + tx];
        As[tx][9] = p.x; As[tx][10] = p.y; As[tx][11] = p.z; As[tx][12] = p.w;
    }

    // Column triangle + plane in registers.
    const int j = C + tx;
    const float* b = tri + (size_t)j * 9;
    float Bv[9];
#pragma unroll
    for (int k = 0; k < 9; ++k) Bv[k] = b[k];
    const float4 pb = planes[j];
    const float nbx = pb.x, nby = pb.y, nbz = pb.z, db = pb.w;

    __syncthreads();

    const int i = R + ty;
    float Av[9];
#pragma unroll
    for (int k = 0; k < 9; ++k) Av[k] = As[ty][k];  // broadcast across tx
    const float nax = As[ty][9], nay = As[ty][10], naz = As[ty][11], da = As[ty][12];

    // Signed distances (left-to-right 3-term dot + offset, then snap).
    float dv[3], du[3];
#pragma unroll
    for (int v = 0; v < 3; ++v) {
        dv[v] = snapz((((Av[3 * v] * nbx) + (Av[3 * v + 1] * nby)) + (Av[3 * v + 2] * nbz)) + db);
        du[v] = snapz((((Bv[3 * v] * nax) + (Bv[3 * v + 1] * nay)) + (Bv[3 * v + 2] * naz)) + da);
    }

    const bool ssv = (dv[0] > 0.0f && dv[1] > 0.0f && dv[2] > 0.0f) ||
                     (dv[0] < 0.0f && dv[1] < 0.0f && dv[2] < 0.0f);
    const bool ssu = (du[0] > 0.0f && du[1] > 0.0f && du[2] > 0.0f) ||
                     (du[0] < 0.0f && du[1] < 0.0f && du[2] < 0.0f);

    // Plane-plane line direction, dominant axis (first-occurrence argmax).
    const float Dx = nay * nbz - naz * nby;
    const float Dy = naz * nbx - nax * nbz;
    const float Dz = nax * nby - nay * nbx;
    const float m0 = fabsf(Dx), m1 = fabsf(Dy), m2 = fabsf(Dz);
    int axm = 0;
    float mm = m0;
    if (m1 > mm) { axm = 1; mm = m1; }
    if (m2 > mm) { axm = 2; }

    float pv[3], pu[3];
#pragma unroll
    for (int v = 0; v < 3; ++v) {
        pv[v] = (axm == 0) ? Av[3 * v] : ((axm == 1) ? Av[3 * v + 1] : Av[3 * v + 2]);
        pu[v] = (axm == 0) ? Bv[3 * v] : ((axm == 1) ? Bv[3 * v + 1] : Bv[3 * v + 2]);
    }

    float t0v, t1v, t0u, t1u;
    tri_interval(pv, dv, t0v, t1v);
    tri_interval(pu, du, t0u, t1u);

    const bool overlap = fmaxf(t0v, t0u) <= fminf(t1v, t1u);
    const bool hit = (!ssv) && (!ssu) && overlap;

    float res = hit ? 1.0f : 0.0f;
    if (i == j) res = 1.0f;

    // Main tile: direct coalesced store from registers.
    out[(size_t)i * n + j] = res;

    // Mirror tile via LDS transpose (stride TS+1=33 -> conflict-free reads).
    if (tr != tc) {
        Sres[ty][tx] = res;
        __syncthreads();
        out[(size_t)(C + ty) * n + (R + tx)] = Sres[tx][ty];
    }
}

extern "C" void kernel_launch(void* const* d_in, const int* in_sizes, int n_in,
                              void* d_out, int out_size, void* d_ws, size_t ws_size,
                              hipStream_t stream) {
    const float* tri = (const float*)d_in[0];
    float* out = (float*)d_out;
    const int n = in_sizes[0] / 9;  // 2048
    float4* planes = (float4*)d_ws;

    plane_kernel<<<(n + 255) / 256, 256, 0, stream>>>(tri, planes, n);

    dim3 block(TS, TS);
    dim3 grid(n / TS, n / TS);  // lower-tri blocks exit immediately
    tile_kernel<<<grid, block, 0, stream>>>(tri, planes, out, n);
}

// Round 4
// 79.517 us; speedup vs baseline: 1.0089x; 1.0089x over previous
//
#include <hip/hip_runtime.h>
#include <math.h>

// Triangle-triangle intersection, bit-exact vs the numpy/JAX reference:
//  - EPS snap at 1e-6, reference op order, fp contract OFF, IEEE divides.
//  - Symmetric: compute only triu 64x64 tiles (linear grid, no dead blocks),
//    mirror written via LDS transpose.
//  - R4 change: ALL global reads are cooperative coalesced float4 staging into
//    LDS (R2/R3 were TA-bound on 9 divergent scalar loads per pair).

static constexpr float EPS_SNAP = 1e-6f;
static constexpr int TS = 64;  // tile size; n=2048 divisible

__device__ __forceinline__ float snapz(float x) {
    return (fabsf(x) < EPS_SNAP) ? 0.0f : x;
}

__device__ __forceinline__ void tri_interval(const float p[3], const float d[3],
                                             float& tmin, float& tmax) {
#pragma clang fp contract(off)
    tmin = INFINITY;
    tmax = -INFINITY;
#pragma unroll
    for (int e = 0; e < 3; ++e) {
        const int i0 = e;
        const int i1 = (e + 1) % 3;  // edges (0,1),(1,2),(2,0)
        const float di = d[i0], dj = d[i1];
        const float pi = p[i0], pj = p[i1];
        const bool valid = (di * dj <= 0.0f) && !((di == 0.0f) && (dj == 0.0f));
        const float denom = di - dj;
        const float dsafe = (denom == 0.0f) ? 1.0f : denom;
        const float t = pi + ((pj - pi) * di) / dsafe;  // ((pj-pi)*di)/denom
        if (valid) {
            tmin = fminf(tmin, t);
            tmax = fmaxf(tmax, t);
        }
    }
}

// Pre-pass: per-triangle plane normal + offset (reference arithmetic order).
__global__ __launch_bounds__(256) void plane_kernel(
    const float* __restrict__ tri, float4* __restrict__ planes, int n)
{
#pragma clang fp contract(off)
    const int i = blockIdx.x * 256 + threadIdx.x;
    if (i >= n) return;
    const float* A = tri + (size_t)i * 9;
    float Av[9];
#pragma unroll
    for (int k = 0; k < 9; ++k) Av[k] = A[k];
    const float e1x = Av[3] - Av[0], e1y = Av[4] - Av[1], e1z = Av[5] - Av[2];
    const float e2x = Av[6] - Av[0], e2y = Av[7] - Av[1], e2z = Av[8] - Av[2];
    const float nx = e1y * e2z - e1z * e2y;
    const float ny = e1z * e2x - e1x * e2z;
    const float nz = e1x * e2y - e1y * e2x;
    const float d = -(((nx * Av[0]) + (ny * Av[1])) + (nz * Av[2]));
    planes[i] = make_float4(nx, ny, nz, d);
}

// Main: 64x64 triu tiles, linear grid (528 blocks for n=2048), block (64,8),
// 8 rows per thread. All global reads coalesced into LDS.
__global__ __launch_bounds__(512, 4) void tile_kernel(
    const float* __restrict__ tri, const float4* __restrict__ planes,
    float* __restrict__ out, int n)
{
#pragma clang fp contract(off)
    const int nt = n / TS;  // 32
    // Linear id -> (tr, tc), tr <= tc. Row tr owns (nt - tr) tiles.
    int k = blockIdx.x, tr = 0;
    while (k >= nt - tr) { k -= nt - tr; ++tr; }
    const int tc = tr + k;
    const int R = tr * TS, C = tc * TS;

    __shared__ float  Asf[TS * 9];       // row triangle verts, [r*9+c]
    __shared__ float  Bsf[TS * 9];       // col triangle verts
    __shared__ float4 Ap[TS], Bp[TS];    // planes
    __shared__ float  Sres[TS][TS + 1];  // result tile for mirror transpose

    const int tx = threadIdx.x;              // 0..63 column in tile
    const int ty = threadIdx.y;              // 0..7
    const int t = ty * TS + tx;              // 0..511

    // Cooperative coalesced staging: 144+144 float4 of verts + 64+64 planes.
    if (t < 144) {
        ((float4*)Asf)[t] = ((const float4*)(tri + (size_t)R * 9))[t];
    } else if (t < 288) {
        ((float4*)Bsf)[t - 144] = ((const float4*)(tri + (size_t)C * 9))[t - 144];
    } else if (t < 352) {
        Ap[t - 288] = planes[R + (t - 288)];
    } else if (t < 416) {
        Bp[t - 352] = planes[C + (t - 352)];
    }
    __syncthreads();

    // Column triangle + plane into registers (stride-9 LDS: 2-way alias, free).
    const int j = C + tx;
    float Bv[9];
#pragma unroll
    for (int kk = 0; kk < 9; ++kk) Bv[kk] = Bsf[tx * 9 + kk];
    const float4 pb = Bp[tx];
    const float nbx = pb.x, nby = pb.y, nbz = pb.z, db = pb.w;

#pragma unroll 2
    for (int kk = 0; kk < 8; ++kk) {
        const int r = ty + 8 * kk;  // 0..63, wave-uniform -> LDS broadcast
        const int i = R + r;

        float Av[9];
#pragma unroll
        for (int q = 0; q < 9; ++q) Av[q] = Asf[r * 9 + q];
        const float4 pa = Ap[r];
        const float nax = pa.x, nay = pa.y, naz = pa.z, da = pa.w;

        // Signed distances (left-to-right 3-term dot + offset, then snap).
        float dv[3], du[3];
#pragma unroll
        for (int v = 0; v < 3; ++v) {
            dv[v] = snapz((((Av[3 * v] * nbx) + (Av[3 * v + 1] * nby)) + (Av[3 * v + 2] * nbz)) + db);
            du[v] = snapz((((Bv[3 * v] * nax) + (Bv[3 * v + 1] * nay)) + (Bv[3 * v + 2] * naz)) + da);
        }

        const bool ssv = (dv[0] > 0.0f && dv[1] > 0.0f && dv[2] > 0.0f) ||
                         (dv[0] < 0.0f && dv[1] < 0.0f && dv[2] < 0.0f);
        const bool ssu = (du[0] > 0.0f && du[1] > 0.0f && du[2] > 0.0f) ||
                         (du[0] < 0.0f && du[1] < 0.0f && du[2] < 0.0f);

        // Plane-plane line direction, dominant axis (first-occurrence argmax).
        const float Dx = nay * nbz - naz * nby;
        const float Dy = naz * nbx - nax * nbz;
        const float Dz = nax * nby - nay * nbx;
        const float m0 = fabsf(Dx), m1 = fabsf(Dy), m2 = fabsf(Dz);
        int axm = 0;
        float mm = m0;
        if (m1 > mm) { axm = 1; mm = m1; }
        if (m2 > mm) { axm = 2; }

        float pv[3], pu[3];
#pragma unroll
        for (int v = 0; v < 3; ++v) {
            pv[v] = (axm == 0) ? Av[3 * v] : ((axm == 1) ? Av[3 * v + 1] : Av[3 * v + 2]);
            pu[v] = (axm == 0) ? Bv[3 * v] : ((axm == 1) ? Bv[3 * v + 1] : Bv[3 * v + 2]);
        }

        float t0v, t1v, t0u, t1u;
        tri_interval(pv, dv, t0v, t1v);
        tri_interval(pu, du, t0u, t1u);

        const bool overlap = fmaxf(t0v, t0u) <= fminf(t1v, t1u);
        const bool hit = (!ssv) && (!ssu) && overlap;

        float res = hit ? 1.0f : 0.0f;
        if (i == j) res = 1.0f;

        out[(size_t)i * n + j] = res;  // coalesced 256B row segments
        Sres[r][tx] = res;
    }

    // Mirror tile (transpose) with coalesced rows; LDS reads 2-way alias only.
    if (tr != tc) {
        __syncthreads();
#pragma unroll 2
        for (int kk = 0; kk < 8; ++kk) {
            const int c = ty + 8 * kk;
            out[(size_t)(C + c) * n + (R + tx)] = Sres[tx][c];
        }
    }
}

extern "C" void kernel_launch(void* const* d_in, const int* in_sizes, int n_in,
                              void* d_out, int out_size, void* d_ws, size_t ws_size,
                              hipStream_t stream) {
    const float* tri = (const float*)d_in[0];
    float* out = (float*)d_out;
    const int n = in_sizes[0] / 9;  // 2048
    float4* planes = (float4*)d_ws;

    plane_kernel<<<(n + 255) / 256, 256, 0, stream>>>(tri, planes, n);

    const int nt = n / TS;
    const int nblocks = nt * (nt + 1) / 2;  // 528
    dim3 block(TS, 8);
    tile_kernel<<<nblocks, block, 0, stream>>>(tri, planes, out, n);
}

// Round 5
// 73.878 us; speedup vs baseline: 1.0859x; 1.0763x over previous
//
#include <hip/hip_runtime.h>
#include <math.h>

// Triangle-triangle intersection, bit-exact vs the numpy/JAX reference.
//  - EPS snap at 1e-6, reference op order, fp contract OFF, IEEE divides.
//  - Symmetric: triu 32x32 tiles (linear grid), mirror via LDS transpose.
//  - R5: two-phase compaction. Phase 1 = cheap mutual-straddle test for all
//    pairs (the reference's own ~ssv & ~ssu gate); survivors are compacted
//    into an LDS queue; phase 2 runs the expensive interval math (6 IEEE
//    divides etc.) only on survivors. R2-R4 showed the kernel is issue-bound
//    on per-pair instruction count -- this cuts the average count ~2x.

static constexpr float EPS_SNAP = 1e-6f;
static constexpr int TS = 32;  // tile size; n=2048 divisible

__device__ __forceinline__ float snapz(float x) {
    return (fabsf(x) < EPS_SNAP) ? 0.0f : x;
}

// Interval of the intersection line covered by one triangle (reference order).
__device__ __forceinline__ void tri_interval(const float p[3], const float d[3],
                                             float& tmin, float& tmax) {
#pragma clang fp contract(off)
    tmin = INFINITY;
    tmax = -INFINITY;
#pragma unroll
    for (int e = 0; e < 3; ++e) {
        const int i0 = e;
        const int i1 = (e + 1) % 3;  // edges (0,1),(1,2),(2,0)
        const float di = d[i0], dj = d[i1];
        const float pi = p[i0], pj = p[i1];
        const bool valid = (di * dj <= 0.0f) && !((di == 0.0f) && (dj == 0.0f));
        const float denom = di - dj;
        const float dsafe = (denom == 0.0f) ? 1.0f : denom;
        const float t = pi + ((pj - pi) * di) / dsafe;  // ((pj-pi)*di)/denom
        if (valid) {
            tmin = fminf(tmin, t);
            tmax = fmaxf(tmax, t);
        }
    }
}

__global__ __launch_bounds__(256, 4) void tile_kernel(
    const float* __restrict__ tri, float* __restrict__ out, int n)
{
#pragma clang fp contract(off)
    const int nt = n / TS;  // 64
    // Linear id -> (tr, tc), tr <= tc.
    int k = blockIdx.x, tr = 0;
    while (k >= nt - tr) { k -= nt - tr; ++tr; }
    const int tc = tr + k;
    const int R = tr * TS, C = tc * TS;

    __shared__ float Asf[TS * 12];        // row tris, padded to 12 floats (b128-able)
    __shared__ float Bsf[TS * 12];        // col tris
    __shared__ float4 Apl[TS], Bpl[TS];   // planes (normal, offset)
    __shared__ float Sres[TS][TS + 1];    // result tile
    __shared__ unsigned short qbuf[TS * TS];  // survivor queue (r<<5|c)
    __shared__ int s_cnt;

    const int tx = threadIdx.x;  // 0..31 column in tile
    const int ty = threadIdx.y;  // 0..7
    const int t = ty * TS + tx;  // 0..255
    const int lane = t & 63;

    // ---- stage verts (coalesced), zero result tile, reset queue ----
    if (t == 0) s_cnt = 0;
    for (int g = t; g < TS * 9; g += 256) {
        const int a = g / 9, c9 = g - a * 9;
        Asf[a * 12 + c9] = tri[(size_t)R * 9 + g];
        Bsf[a * 12 + c9] = tri[(size_t)C * 9 + g];
    }
    for (int g = t; g < TS * (TS + 1); g += 256) ((float*)Sres)[g] = 0.0f;
    __syncthreads();

    // ---- per-triangle planes (reference arithmetic order) ----
    if (t < 2 * TS) {
        const float* V = (t < TS) ? &Asf[t * 12] : &Bsf[(t - TS) * 12];
        const float e1x = V[3] - V[0], e1y = V[4] - V[1], e1z = V[5] - V[2];
        const float e2x = V[6] - V[0], e2y = V[7] - V[1], e2z = V[8] - V[2];
        const float nx = e1y * e2z - e1z * e2y;
        const float ny = e1z * e2x - e1x * e2z;
        const float nz = e1x * e2y - e1y * e2x;
        const float d = -(((nx * V[0]) + (ny * V[1])) + (nz * V[2]));
        if (t < TS) Apl[t] = make_float4(nx, ny, nz, d);
        else        Bpl[t - TS] = make_float4(nx, ny, nz, d);
    }
    if (tr == tc && t < TS) Sres[t][t] = 1.0f;  // identity on the diagonal
    __syncthreads();

    // ---- phase 1: mutual-straddle gate for all pairs, compact survivors ----
    float Bv[9];
    {
        const float4 b0 = *(const float4*)&Bsf[tx * 12];
        const float4 b1 = *(const float4*)&Bsf[tx * 12 + 4];
        const float4 b2 = *(const float4*)&Bsf[tx * 12 + 8];
        Bv[0] = b0.x; Bv[1] = b0.y; Bv[2] = b0.z; Bv[3] = b0.w;
        Bv[4] = b1.x; Bv[5] = b1.y; Bv[6] = b1.z; Bv[7] = b1.w;
        Bv[8] = b2.x;
    }
    const float4 pb = Bpl[tx];

    for (int kk = 0; kk < 4; ++kk) {
        const int r = ty + 8 * kk;
        const float4 a0 = *(const float4*)&Asf[r * 12];
        const float4 a1 = *(const float4*)&Asf[r * 12 + 4];
        const float4 a2 = *(const float4*)&Asf[r * 12 + 8];
        const float4 pa = Apl[r];
        // snapped signed distances (left-to-right dot + offset, ref order)
        const float dv0 = snapz((((a0.x * pb.x) + (a0.y * pb.y)) + (a0.z * pb.z)) + pb.w);
        const float dv1 = snapz((((a0.w * pb.x) + (a1.x * pb.y)) + (a1.y * pb.z)) + pb.w);
        const float dv2 = snapz((((a1.z * pb.x) + (a1.w * pb.y)) + (a2.x * pb.z)) + pb.w);
        const float du0 = snapz((((Bv[0] * pa.x) + (Bv[1] * pa.y)) + (Bv[2] * pa.z)) + pa.w);
        const float du1 = snapz((((Bv[3] * pa.x) + (Bv[4] * pa.y)) + (Bv[5] * pa.z)) + pa.w);
        const float du2 = snapz((((Bv[6] * pa.x) + (Bv[7] * pa.y)) + (Bv[8] * pa.z)) + pa.w);
        // all-one-side tests via min3/max3 (exact: no NaNs here)
        const float mnv = fminf(fminf(dv0, dv1), dv2), mxv = fmaxf(fmaxf(dv0, dv1), dv2);
        const float mnu = fminf(fminf(du0, du1), du2), mxu = fmaxf(fmaxf(du0, du1), du2);
        const bool ssv = (mnv > 0.0f) || (mxv < 0.0f);
        const bool ssu = (mnu > 0.0f) || (mxu < 0.0f);
        const bool surv = !ssv && !ssu && ((R + r) != (C + tx));  // diag preset to 1
        // wave-aggregated enqueue
        const unsigned long long m = __ballot(surv);
        int wb = 0;
        if (lane == 0) {
            const int wcnt = __popcll(m);
            if (wcnt) wb = atomicAdd(&s_cnt, wcnt);
        }
        wb = __shfl(wb, 0);
        if (surv) {
            const int pos = wb + __popcll(m & ((1ull << lane) - 1ull));
            qbuf[pos] = (unsigned short)((r << 5) | tx);
        }
    }
    __syncthreads();

    // ---- phase 2: full interval test on survivors only ----
    const int total = s_cnt;
    for (int q = t; q < total; q += 256) {
        const int e = qbuf[q];
        const int r = e >> 5, c = e & 31;

        float Av[9], Bw[9];
        {
            const float4 a0 = *(const float4*)&Asf[r * 12];
            const float4 a1 = *(const float4*)&Asf[r * 12 + 4];
            const float4 a2 = *(const float4*)&Asf[r * 12 + 8];
            Av[0] = a0.x; Av[1] = a0.y; Av[2] = a0.z; Av[3] = a0.w;
            Av[4] = a1.x; Av[5] = a1.y; Av[6] = a1.z; Av[7] = a1.w;
            Av[8] = a2.x;
            const float4 b0 = *(const float4*)&Bsf[c * 12];
            const float4 b1 = *(const float4*)&Bsf[c * 12 + 4];
            const float4 b2 = *(const float4*)&Bsf[c * 12 + 8];
            Bw[0] = b0.x; Bw[1] = b0.y; Bw[2] = b0.z; Bw[3] = b0.w;
            Bw[4] = b1.x; Bw[5] = b1.y; Bw[6] = b1.z; Bw[7] = b1.w;
            Bw[8] = b2.x;
        }
        const float4 pa = Apl[r];
        const float4 pq = Bpl[c];
        const float nax = pa.x, nay = pa.y, naz = pa.z, da = pa.w;
        const float nbx = pq.x, nby = pq.y, nbz = pq.z, db = pq.w;

        // recompute snapped distances (bitwise identical to phase 1)
        float dv[3], du[3];
#pragma unroll
        for (int v = 0; v < 3; ++v) {
            dv[v] = snapz((((Av[3 * v] * nbx) + (Av[3 * v + 1] * nby)) + (Av[3 * v + 2] * nbz)) + db);
            du[v] = snapz((((Bw[3 * v] * nax) + (Bw[3 * v + 1] * nay)) + (Bw[3 * v + 2] * naz)) + da);
        }

        // plane-plane line direction, dominant axis (first-occurrence argmax)
        const float Dx = nay * nbz - naz * nby;
        const float Dy = naz * nbx - nax * nbz;
        const float Dz = nax * nby - nay * nbx;
        const float m0 = fabsf(Dx), m1 = fabsf(Dy), m2 = fabsf(Dz);
        int axm = 0;
        float mm = m0;
        if (m1 > mm) { axm = 1; mm = m1; }
        if (m2 > mm) { axm = 2; }

        float pv[3], pu[3];
#pragma unroll
        for (int v = 0; v < 3; ++v) {
            pv[v] = (axm == 0) ? Av[3 * v] : ((axm == 1) ? Av[3 * v + 1] : Av[3 * v + 2]);
            pu[v] = (axm == 0) ? Bw[3 * v] : ((axm == 1) ? Bw[3 * v + 1] : Bw[3 * v + 2]);
        }

        float t0v, t1v, t0u, t1u;
        tri_interval(pv, dv, t0v, t1v);
        tri_interval(pu, du, t0u, t1u);

        const bool overlap = fmaxf(t0v, t0u) <= fminf(t1v, t1u);
        Sres[r][c] = overlap ? 1.0f : 0.0f;  // queued => ~ssv & ~ssu already
    }
    __syncthreads();

    // ---- write out tile (+ mirror), coalesced float4 ----
    {
        const int row = t >> 3;          // 0..31
        const int c4 = (t & 7) * 4;      // 0,4,...,28
        float4 v;
        v.x = Sres[row][c4 + 0]; v.y = Sres[row][c4 + 1];
        v.z = Sres[row][c4 + 2]; v.w = Sres[row][c4 + 3];
        *(float4*)&out[(size_t)(R + row) * n + C + c4] = v;
        if (tr != tc) {
            float4 w;
            w.x = Sres[c4 + 0][row]; w.y = Sres[c4 + 1][row];
            w.z = Sres[c4 + 2][row]; w.w = Sres[c4 + 3][row];
            *(float4*)&out[(size_t)(C + row) * n + R + c4] = w;
        }
    }
}

extern "C" void kernel_launch(void* const* d_in, const int* in_sizes, int n_in,
                              void* d_out, int out_size, void* d_ws, size_t ws_size,
                              hipStream_t stream) {
    const float* tri = (const float*)d_in[0];
    float* out = (float*)d_out;
    const int n = in_sizes[0] / 9;  // 2048

    const int nt = n / TS;                   // 64
    const int nblocks = nt * (nt + 1) / 2;   // 2080 triu tiles
    dim3 block(TS, 8);
    tile_kernel<<<nblocks, block, 0, stream>>>(tri, out, n);
}